// Round 14
// baseline (478.242 us; speedup 1.0000x reference)
//
#include <hip/hip_runtime.h>
#include <hip/hip_bf16.h>

// ---------------------------------------------------------------------------
// ROUND 14: occupancy fix for k_attn_mfma. R13 counters: Occupancy 11%
// (1 wave/SIMD, grid-limited), HBM 566 GB/s (9%), VALU 20%, 2450 cyc/iter
// (= HBM latency exposed). Changes:
//  (1) j-split attention into njy column slices (grid 500 x njy) with
//      per-slice partial Acc/S, combined in k_final. njy tiered by ws_size
//      (4 / 2 / 1); partAcc overlays Whf (dead after k_bpack).
//  (2) mask prefetch depth 2 -> 3.
//  (3) k_wh: unroll x2 + split accumulators (ILP).
// Semantics identical to the R12/R13-verified baseline.
// ---------------------------------------------------------------------------

#define CN1 3000
#define CN2 2500
#define CN3 2500
#define NTOT 8000
#define INF_ 128
#define OUTF 64
#define LOG2E 1.44269504088896340736f
#define ALPHA 0.2f

typedef __attribute__((ext_vector_type(4))) float f32x4;
typedef __attribute__((ext_vector_type(8))) short short8;
union B16x8 { int4 i4; short8 s8; unsigned int u[4]; };

#if defined(__has_builtin)
#if __has_builtin(__builtin_amdgcn_exp2f)
#define EXP2F(x) __builtin_amdgcn_exp2f(x)
#endif
#endif
#ifndef EXP2F
#define EXP2F(x) exp2f(x)
#endif

__device__ inline float wave_sum(float v) {
  for (int d = 32; d; d >>= 1) v += __shfl_xor(v, d, 64);
  return v;
}

__device__ inline unsigned int pack2_bf16(float a, float b) {
  unsigned ua = __float_as_uint(a);
  ua = (ua + 0x7FFFu + ((ua >> 16) & 1u)) >> 16;
  unsigned ub = __float_as_uint(b);
  ub = (ub + 0x7FFFu + ((ub >> 16) & 1u)) & 0xFFFF0000u;
  return ub | ua;
}

// ---------------- k_detect ---------------------------------------------------
__global__ void k_detect(const unsigned int* __restrict__ hw, int* __restrict__ flag) {
  unsigned int w = hw[threadIdx.x];
  int lo_e = (w >> 7) & 0xFF;
  int hi_e = (w >> 23) & 0xFF;
  int ok = (lo_e >= 64 && lo_e <= 143 && hi_e >= 64 && hi_e <= 143) ? 1 : 0;
  for (int d = 32; d; d >>= 1) ok += __shfl_xor(ok, d, 64);
  if (threadIdx.x == 0) flag[0] = (ok >= 48) ? 1 : 0;
}

// ---------------- k_wh: block=128 (2 waves = 2 nodes), grid=4000 ------------
__global__ void k_wh(const void* __restrict__ hv_, const void* __restrict__ Wsv_,
                     const void* __restrict__ apv_, const int* __restrict__ flag,
                     float* __restrict__ Whf,    // [2][8000][64]
                     float* __restrict__ Wh1s,   // [2][8000] = (Wh·a1)*log2e
                     float* __restrict__ Wh2s) { // [2][8000] = (Wh·a2)*log2e
  const int t = threadIdx.x;
  const int o = t & 63;
  const int n = blockIdx.x * 2 + (t >> 6);
  const bool isbf = (flag[0] != 0);
  float acc0, acc1;
  float ap0, ap1, ap2, ap3;
  if (isbf) {
    const __hip_bfloat16* hrow = (const __hip_bfloat16*)hv_ + n * INF_;
    const __hip_bfloat16* Ws = (const __hip_bfloat16*)Wsv_;
    const __hip_bfloat16* ap = (const __hip_bfloat16*)apv_;
    acc0 = 0.f; acc1 = 0.f;
    for (int f = 0; f < INF_; ++f) {
      float hv = __bfloat162float(hrow[f]);
      acc0 += hv * __bfloat162float(Ws[f * OUTF + o]);
      acc1 += hv * __bfloat162float(Ws[INF_ * OUTF + f * OUTF + o]);
    }
    ap0 = __bfloat162float(ap[o]);            ap1 = __bfloat162float(ap[OUTF + o]);
    ap2 = __bfloat162float(ap[2 * OUTF + o]); ap3 = __bfloat162float(ap[3 * OUTF + o]);
  } else {
    const float* hrow = (const float*)hv_ + n * INF_;
    const float* Ws0 = (const float*)Wsv_ + o;
    const float* Ws1 = (const float*)Wsv_ + INF_ * OUTF + o;
    const float* ap = (const float*)apv_;
    float a0a = 0.f, a0b = 0.f, a1a = 0.f, a1b = 0.f;
#pragma unroll 8
    for (int f = 0; f < INF_; f += 2) {
      float h0 = hrow[f], h1 = hrow[f + 1];
      a0a += h0 * Ws0[f * OUTF];
      a0b += h1 * Ws0[(f + 1) * OUTF];
      a1a += h0 * Ws1[f * OUTF];
      a1b += h1 * Ws1[(f + 1) * OUTF];
    }
    acc0 = a0a + a0b; acc1 = a1a + a1b;
    ap0 = ap[o]; ap1 = ap[OUTF + o]; ap2 = ap[2 * OUTF + o]; ap3 = ap[3 * OUTF + o];
  }
  Whf[(0 * NTOT + n) * OUTF + o] = acc0;
  Whf[(1 * NTOT + n) * OUTF + o] = acc1;
  float s10 = wave_sum(acc0 * ap0);
  float s20 = wave_sum(acc0 * ap1);
  float s11 = wave_sum(acc1 * ap2);
  float s21 = wave_sum(acc1 * ap3);
  if (o == 0) {
    Wh1s[n] = s10 * LOG2E;        Wh2s[n] = s20 * LOG2E;
    Wh1s[NTOT + n] = s11 * LOG2E; Wh2s[NTOT + n] = s21 * LOG2E;
  }
}

// ---------------- k_m2 -------------------------------------------------------
__global__ void k_m2(const float* __restrict__ Wh2s, float* __restrict__ M2s) {
  const int hd = blockIdx.x;
  float mx = -1e30f;
  for (int i = threadIdx.x; i < NTOT; i += 256)
    mx = fmaxf(mx, Wh2s[hd * NTOT + i]);
  for (int d = 32; d; d >>= 1) mx = fmaxf(mx, __shfl_xor(mx, d, 64));
  __shared__ float red[4];
  if ((threadIdx.x & 63) == 0) red[threadIdx.x >> 6] = mx;
  __syncthreads();
  if (threadIdx.x == 0)
    M2s[hd] = fmaxf(fmaxf(red[0], red[1]), fmaxf(red[2], red[3]));
}

// ---------------- k_bpack: Wh -> bf16 B-fragments ---------------------------
__global__ void k_bpack(const float* __restrict__ Whf, int4* __restrict__ WhB) {
  const int gid = blockIdx.x * 256 + threadIdx.x;  // 128000 total
  const int lane = gid & 63;
  const int c = (gid >> 6) & 3;
  const int t = (gid >> 8) % 250;
  const int hd = gid / 64000;
  const int jb = t * 32 + (lane >> 4) * 8;
  const int col = c * 16 + (lane & 15);
  const float* src = Whf + (hd * NTOT + jb) * OUTF + col;
  B16x8 out;
#pragma unroll
  for (int e2 = 0; e2 < 4; ++e2)
    out.u[e2] = pack2_bf16(src[(2 * e2) * OUTF], src[(2 * e2 + 1) * OUTF]);
  WhB[gid] = out.i4;
}

// ---------------- k_attn_mfma: grid=(500, njy), block=128 (wave = head) -----
__global__ __launch_bounds__(128)
void k_attn_mfma(const int* __restrict__ A1,  const int* __restrict__ A12, const int* __restrict__ A13,
                 const int* __restrict__ A21, const int* __restrict__ A2,  const int* __restrict__ A23,
                 const int* __restrict__ A31, const int* __restrict__ A32, const int* __restrict__ A3,
                 const float* __restrict__ Wh1s, const float* __restrict__ Wh2s,
                 const float* __restrict__ M2s, const int4* __restrict__ WhB,
                 float* __restrict__ partAcc,   // [njy][2][8000][64]
                 float* __restrict__ partS)     // [njy][2][8000]
{
  const int hd = threadIdx.x >> 6;     // wave = head
  const int lane = threadIdx.x & 63;
  const int m = lane & 15;
  const int g = lane >> 4;
  const int kb = g * 8;
  const int i = blockIdx.x * 16 + m;
  const int jy = blockIdx.y, njy = gridDim.y;
  const int t0 = (250 * jy) / njy, t1 = (250 * (jy + 1)) / njy;

  const int *p0, *p1, *p2;
  if (i < CN1)            { p0 = A1  + i * CN1;          p1 = A12 + i * CN2;          p2 = A13 + i * CN3; }
  else if (i < CN1 + CN2) { int r = i - CN1;       p0 = A21 + r * CN1; p1 = A2  + r * CN2; p2 = A23 + r * CN3; }
  else                    { int r = i - CN1 - CN2; p0 = A31 + r * CN1; p1 = A32 + r * CN2; p2 = A3  + r * CN3; }

  const float w1s = Wh1s[hd * NTOT + i];
  const float y   = w1s + M2s[hd];
  const float ci  = fmaxf(y, ALPHA * y);
  const float a1c = w1s - ci;
  const float b1c = ALPHA * w1s - ci;
  const float* wh2 = Wh2s + hd * NTOT;

  f32x4 acc0 = {0.f, 0.f, 0.f, 0.f};
  f32x4 acc1 = acc0, acc2 = acc0, acc3 = acc0;
  float s_part = 0.f;

  auto load_mask = [&](int t, int4& ma, int4& mb) {
    int j8 = t * 32 + kb;
    if (j8 >= CN1 + CN2) {
      const int4* q = (const int4*)(p2 + (j8 - CN1 - CN2));
      ma = q[0]; mb = q[1];
    } else if (j8 >= CN1) {
      if (j8 + 8 <= CN1 + CN2) {
        const int4* q = (const int4*)(p1 + (j8 - CN1));
        ma = q[0]; mb = q[1];
      } else {
        int v[8];
#pragma unroll
        for (int e = 0; e < 8; ++e) {
          int je = j8 + e;
          v[e] = (je < CN1 + CN2) ? p1[je - CN1] : p2[je - CN1 - CN2];
        }
        ma = make_int4(v[0], v[1], v[2], v[3]);
        mb = make_int4(v[4], v[5], v[6], v[7]);
      }
    } else {
      const int4* q = (const int4*)(p0 + j8);
      ma = q[0]; mb = q[1];
    }
  };

  auto load_frags = [&](int t, int4& b0, int4& b1, int4& b2, int4& b3,
                        float4& wa, float4& wb) {
    const int4* bp = WhB + (hd * 250 + t) * 256 + lane;
    b0 = bp[0]; b1 = bp[64]; b2 = bp[128]; b3 = bp[192];
    const float* w = wh2 + t * 32 + kb;
    wa = *(const float4*)w;
    wb = *(const float4*)(w + 4);
  };

  auto compute = [&](const int4& ma, const int4& mb, const float4& wa, const float4& wb,
                     const int4& b0, const int4& b1, const int4& b2, const int4& b3) {
    const float wv[8] = {wa.x, wa.y, wa.z, wa.w, wb.x, wb.y, wb.z, wb.w};
    const int   mv[8] = {ma.x, ma.y, ma.z, ma.w, mb.x, mb.y, mb.z, mb.w};
    float p[8];
#pragma unroll
    for (int e = 0; e < 8; ++e) {
      float xa = a1c + wv[e];
      float xb = fmaf(ALPHA, wv[e], b1c);
      float pe = EXP2F(fmaxf(xa, xb));
      p[e] = (mv[e] > 0) ? pe : 0.f;
    }
    s_part += ((p[0] + p[1]) + (p[2] + p[3])) + ((p[4] + p[5]) + (p[6] + p[7]));
    B16x8 af;
#pragma unroll
    for (int e2 = 0; e2 < 4; ++e2) af.u[e2] = pack2_bf16(p[2 * e2], p[2 * e2 + 1]);
    B16x8 f0, f1, f2, f3;
    f0.i4 = b0; f1.i4 = b1; f2.i4 = b2; f3.i4 = b3;
    acc0 = __builtin_amdgcn_mfma_f32_16x16x32_bf16(af.s8, f0.s8, acc0, 0, 0, 0);
    acc1 = __builtin_amdgcn_mfma_f32_16x16x32_bf16(af.s8, f1.s8, acc1, 0, 0, 0);
    acc2 = __builtin_amdgcn_mfma_f32_16x16x32_bf16(af.s8, f2.s8, acc2, 0, 0, 0);
    acc3 = __builtin_amdgcn_mfma_f32_16x16x32_bf16(af.s8, f3.s8, acc3, 0, 0, 0);
  };

  // software pipeline: mask 3 ahead (HBM), frags 1 ahead (L2/L3)
  int4 ma0, mb0, ma1, mb1, ma2, mb2, ma3, mb3;
  int4 b0, b1, b2, b3; float4 wa, wb;
  load_mask(t0, ma0, mb0);
  load_mask(min(t0 + 1, t1 - 1), ma1, mb1);
  load_mask(min(t0 + 2, t1 - 1), ma2, mb2);
  load_frags(t0, b0, b1, b2, b3, wa, wb);
  for (int t = t0; t < t1; ++t) {
    int4 nb0, nb1, nb2, nb3; float4 nwa, nwb;
    load_frags(min(t + 1, t1 - 1), nb0, nb1, nb2, nb3, nwa, nwb);
    load_mask(min(t + 3, t1 - 1), ma3, mb3);
    compute(ma0, mb0, wa, wb, b0, b1, b2, b3);
    ma0 = ma1; mb0 = mb1; ma1 = ma2; mb1 = mb2; ma2 = ma3; mb2 = mb3;
    b0 = nb0; b1 = nb1; b2 = nb2; b3 = nb3; wa = nwa; wb = nwb;
  }

  // row sums: row m lives on lanes {m, m+16, m+32, m+48}
  float s_full = s_part;
  s_full += __shfl_xor(s_full, 16, 64);
  s_full += __shfl_xor(s_full, 32, 64);
  const int base = (jy * 2 + hd) * NTOT;
  if (lane < 16) partS[base + blockIdx.x * 16 + lane] = s_full;

  // C layout: col = lane&15 (feature), row = g*4 + q (node)
  float* outp = partAcc + (base + blockIdx.x * 16) * OUTF;
#pragma unroll
  for (int q = 0; q < 4; ++q) {
    const int row = g * 4 + q;
    outp[row * OUTF +      m] = acc0[q];
    outp[row * OUTF + 16 + m] = acc1[q];
    outp[row * OUTF + 32 + m] = acc2[q];
    outp[row * OUTF + 48 + m] = acc3[q];
  }
}

// ---------------- k_final: combine njy + /s + ELU + log_softmax + store -----
__global__ void k_final(const float* __restrict__ partAcc, const float* __restrict__ partS,
                        int njy, float* __restrict__ out) {
  const int wave = threadIdx.x >> 6, lane = threadIdx.x & 63;
  const int n = blockIdx.x * 4 + wave;
  float x[2];
#pragma unroll
  for (int hd = 0; hd < 2; ++hd) {
    float a = 0.f, s = 0.f;
    for (int jy = 0; jy < njy; ++jy) {
      a += partAcc[((jy * 2 + hd) * NTOT + n) * OUTF + lane];
      s += partS[(jy * 2 + hd) * NTOT + n];
    }
    float mid = a / s;
    x[hd] = mid > 0.f ? mid : (__expf(mid) - 1.f);   // ELU(alpha=1)
  }
  float mx = fmaxf(x[0], x[1]);
  for (int d = 32; d; d >>= 1) mx = fmaxf(mx, __shfl_xor(mx, d, 64));
  float se = __expf(x[0] - mx) + __expf(x[1] - mx);
  for (int d = 32; d; d >>= 1) se += __shfl_xor(se, d, 64);
  const float lse = mx + __logf(se);
  const int orow = (n >= CN1 + CN2) ? (n - CN1 - CN2) : (n + CN3);
  out[orow * 128 + lane]      = x[0] - lse;
  out[orow * 128 + 64 + lane] = x[1] - lse;
}

__global__ void k_sentinel(float* __restrict__ out, float v) {
  out[blockIdx.x * 256 + threadIdx.x] = v;
}

// ---------------------------------------------------------------------------
extern "C" void kernel_launch(void* const* d_in, const int* in_sizes, int n_in,
                              void* d_out, int out_size, void* d_ws, size_t ws_size,
                              hipStream_t stream) {
  float* outf = (float*)d_out;

  static const int EXP[12] = {1024000, 9000000, 6250000, 6250000, 7500000, 7500000,
                              6250000, 7500000, 7500000, 6250000, 16384, 256};
  bool exact = (n_in == 12);
  if (exact) for (int i = 0; i < 12; ++i) if (in_sizes[i] != EXP[i]) { exact = false; break; }

  // workspace layout (partAcc overlays Whf, which is dead after k_bpack):
  //   0:         Wh1s   64,000
  //   64,000:    Wh2s   64,000
  //   128,000:   M2s       256
  //   128,256:   flag      256
  //   128,512:   WhB  2,048,000
  //   2,176,512: partS  256,000  (njy<=4)
  //   2,432,512: Whf  4,096,000 | partAcc njy*4,096,000
  const size_t BASE = 2432512;
  int njy = (ws_size >= BASE + 4ull * 4096000) ? 4
          : (ws_size >= BASE + 2ull * 4096000) ? 2
          : (ws_size >= BASE + 1ull * 4096000) ? 1 : 0;
  if (!exact || njy == 0) {
    k_sentinel<<<dim3(4000), dim3(256), 0, stream>>>(outf, -148.0f);
    return;
  }

  const void* h  = d_in[0];
  const int* A1  = (const int*)d_in[1];
  const int* A2  = (const int*)d_in[2];
  const int* A3  = (const int*)d_in[3];
  const int* A12 = (const int*)d_in[4];
  const int* A13 = (const int*)d_in[5];
  const int* A23 = (const int*)d_in[6];
  const int* A21 = (const int*)d_in[7];
  const int* A31 = (const int*)d_in[8];
  const int* A32 = (const int*)d_in[9];
  const void* Ws = d_in[10];
  const void* ap = d_in[11];

  char* w = (char*)d_ws;
  float* Wh1s    = (float*)(w);
  float* Wh2s    = (float*)(w + 64000);
  float* M2s     = (float*)(w + 128000);
  int*   flag    = (int*)  (w + 128256);
  int4*  WhB     = (int4*) (w + 128512);
  float* partS   = (float*)(w + 2176512);
  float* Whf     = (float*)(w + 2432512);
  float* partAcc = (float*)(w + 2432512);   // overlays Whf

  k_detect   <<<dim3(1),        dim3(64),  0, stream>>>((const unsigned int*)h, flag);
  k_wh       <<<dim3(4000),     dim3(128), 0, stream>>>(h, Ws, ap, flag, Whf, Wh1s, Wh2s);
  k_m2       <<<dim3(2),        dim3(256), 0, stream>>>(Wh2s, M2s);
  k_bpack    <<<dim3(500),      dim3(256), 0, stream>>>(Whf, WhB);
  k_attn_mfma<<<dim3(500, njy), dim3(128), 0, stream>>>(A1, A12, A13, A21, A2, A23, A31, A32, A3,
                                                        Wh1s, Wh2s, M2s, WhB, partAcc, partS);
  k_final    <<<dim3(2000),     dim3(256), 0, stream>>>(partAcc, partS, njy, outf);
}

// Round 15
// 407.854 us; speedup vs baseline: 1.1726x; 1.1726x over previous
//
#include <hip/hip_runtime.h>
#include <hip/hip_bf16.h>

// ---------------------------------------------------------------------------
// ROUND 15: merged-head attention wave. R13 vs R14 proved a shared ceiling:
// same 250K wave-iterations, same ~260us at 1x and 4x occupancy => scattered
// mask-line demand (512 MB/launch: BOTH head-waves read the SAME mask rows)
// saturates DRAM at ~1.9 TB/s effective. One wave now computes both heads
// from one copy of the mask regs => mask demand halves to its 256 MB floor,
// stream count halves. 8 MFMA/iter, 2x4 f32x4 accs, launch_bounds(128,2).
// Also: k_detect dropped (fp32 proven), k_wh fp32-only.
// ---------------------------------------------------------------------------

#define CN1 3000
#define CN2 2500
#define CN3 2500
#define NTOT 8000
#define INF_ 128
#define OUTF 64
#define LOG2E 1.44269504088896340736f
#define ALPHA 0.2f

typedef __attribute__((ext_vector_type(4))) float f32x4;
typedef __attribute__((ext_vector_type(8))) short short8;
union B16x8 { int4 i4; short8 s8; unsigned int u[4]; };

#if defined(__has_builtin)
#if __has_builtin(__builtin_amdgcn_exp2f)
#define EXP2F(x) __builtin_amdgcn_exp2f(x)
#endif
#endif
#ifndef EXP2F
#define EXP2F(x) exp2f(x)
#endif

__device__ inline float wave_sum(float v) {
  for (int d = 32; d; d >>= 1) v += __shfl_xor(v, d, 64);
  return v;
}

__device__ inline unsigned int pack2_bf16(float a, float b) {
  unsigned ua = __float_as_uint(a);
  ua = (ua + 0x7FFFu + ((ua >> 16) & 1u)) >> 16;
  unsigned ub = __float_as_uint(b);
  ub = (ub + 0x7FFFu + ((ub >> 16) & 1u)) & 0xFFFF0000u;
  return ub | ua;
}

// ---------------- k_wh: block=128 (2 waves = 2 nodes), grid=4000, fp32 ------
__global__ void k_wh(const float* __restrict__ hv, const float* __restrict__ Wsv,
                     const float* __restrict__ ap,
                     float* __restrict__ Whf,    // [2][8000][64]
                     float* __restrict__ Wh1s,   // [2][8000] = (Wh·a1)*log2e
                     float* __restrict__ Wh2s) { // [2][8000] = (Wh·a2)*log2e
  const int t = threadIdx.x;
  const int o = t & 63;
  const int n = blockIdx.x * 2 + (t >> 6);
  const float* hrow = hv + n * INF_;
  const float* Ws0 = Wsv + o;
  const float* Ws1 = Wsv + INF_ * OUTF + o;
  float a0a = 0.f, a0b = 0.f, a1a = 0.f, a1b = 0.f;
#pragma unroll 8
  for (int f = 0; f < INF_; f += 2) {
    float h0 = hrow[f], h1 = hrow[f + 1];
    a0a += h0 * Ws0[f * OUTF];
    a0b += h1 * Ws0[(f + 1) * OUTF];
    a1a += h0 * Ws1[f * OUTF];
    a1b += h1 * Ws1[(f + 1) * OUTF];
  }
  float acc0 = a0a + a0b, acc1 = a1a + a1b;
  Whf[(0 * NTOT + n) * OUTF + o] = acc0;
  Whf[(1 * NTOT + n) * OUTF + o] = acc1;
  float s10 = wave_sum(acc0 * ap[o]);
  float s20 = wave_sum(acc0 * ap[OUTF + o]);
  float s11 = wave_sum(acc1 * ap[2 * OUTF + o]);
  float s21 = wave_sum(acc1 * ap[3 * OUTF + o]);
  if (o == 0) {
    Wh1s[n] = s10 * LOG2E;        Wh2s[n] = s20 * LOG2E;
    Wh1s[NTOT + n] = s11 * LOG2E; Wh2s[NTOT + n] = s21 * LOG2E;
  }
}

// ---------------- k_m2 -------------------------------------------------------
__global__ void k_m2(const float* __restrict__ Wh2s, float* __restrict__ M2s) {
  const int hd = blockIdx.x;
  float mx = -1e30f;
  for (int i = threadIdx.x; i < NTOT; i += 256)
    mx = fmaxf(mx, Wh2s[hd * NTOT + i]);
  for (int d = 32; d; d >>= 1) mx = fmaxf(mx, __shfl_xor(mx, d, 64));
  __shared__ float red[4];
  if ((threadIdx.x & 63) == 0) red[threadIdx.x >> 6] = mx;
  __syncthreads();
  if (threadIdx.x == 0)
    M2s[hd] = fmaxf(fmaxf(red[0], red[1]), fmaxf(red[2], red[3]));
}

// ---------------- k_bpack: Wh -> bf16 B-fragments ---------------------------
__global__ void k_bpack(const float* __restrict__ Whf, int4* __restrict__ WhB) {
  const int gid = blockIdx.x * 256 + threadIdx.x;  // 128000 total
  const int lane = gid & 63;
  const int c = (gid >> 6) & 3;
  const int t = (gid >> 8) % 250;
  const int hd = gid / 64000;
  const int jb = t * 32 + (lane >> 4) * 8;
  const int col = c * 16 + (lane & 15);
  const float* src = Whf + (hd * NTOT + jb) * OUTF + col;
  B16x8 out;
#pragma unroll
  for (int e2 = 0; e2 < 4; ++e2)
    out.u[e2] = pack2_bf16(src[(2 * e2) * OUTF], src[(2 * e2 + 1) * OUTF]);
  WhB[gid] = out.i4;
}

// ---------------- k_attn_mfma: grid=(250, njy), block=128 -------------------
// wave = 16 rows x BOTH heads (mask read once per row per launch).
__global__ __launch_bounds__(128, 2)
void k_attn_mfma(const int* __restrict__ A1,  const int* __restrict__ A12, const int* __restrict__ A13,
                 const int* __restrict__ A21, const int* __restrict__ A2,  const int* __restrict__ A23,
                 const int* __restrict__ A31, const int* __restrict__ A32, const int* __restrict__ A3,
                 const float* __restrict__ Wh1s, const float* __restrict__ Wh2s,
                 const float* __restrict__ M2s, const int4* __restrict__ WhB,
                 float* __restrict__ partAcc,   // [njy][2][8000][64]
                 float* __restrict__ partS)     // [njy][2][8000]
{
  const int widx = threadIdx.x >> 6;
  const int lane = threadIdx.x & 63;
  const int m = lane & 15;
  const int g = lane >> 4;
  const int kb = g * 8;
  const int rowblk = blockIdx.x * 2 + widx;      // 0..499
  const int i = rowblk * 16 + m;
  const int jy = blockIdx.y, njy = gridDim.y;
  const int t0 = (250 * jy) / njy, t1 = (250 * (jy + 1)) / njy;

  const int *p0, *p1, *p2;
  if (i < CN1)            { p0 = A1  + i * CN1;          p1 = A12 + i * CN2;          p2 = A13 + i * CN3; }
  else if (i < CN1 + CN2) { int r = i - CN1;       p0 = A21 + r * CN1; p1 = A2  + r * CN2; p2 = A23 + r * CN3; }
  else                    { int r = i - CN1 - CN2; p0 = A31 + r * CN1; p1 = A32 + r * CN2; p2 = A3  + r * CN3; }

  const float w1s0 = Wh1s[i],        w1s1 = Wh1s[NTOT + i];
  const float y0 = w1s0 + M2s[0],    y1 = w1s1 + M2s[1];
  const float ci0 = fmaxf(y0, ALPHA * y0), ci1 = fmaxf(y1, ALPHA * y1);
  const float a1c0 = w1s0 - ci0, b1c0 = ALPHA * w1s0 - ci0;
  const float a1c1 = w1s1 - ci1, b1c1 = ALPHA * w1s1 - ci1;
  const float* wh2_0 = Wh2s;
  const float* wh2_1 = Wh2s + NTOT;

  f32x4 a0_0 = {0.f,0.f,0.f,0.f}, a0_1 = a0_0, a0_2 = a0_0, a0_3 = a0_0;
  f32x4 a1_0 = a0_0, a1_1 = a0_0, a1_2 = a0_0, a1_3 = a0_0;
  float sp0 = 0.f, sp1 = 0.f;

  auto load_mask = [&](int t, int4& ma, int4& mb) {
    int j8 = t * 32 + kb;
    if (j8 >= CN1 + CN2) {
      const int4* q = (const int4*)(p2 + (j8 - CN1 - CN2));
      ma = q[0]; mb = q[1];
    } else if (j8 >= CN1) {
      if (j8 + 8 <= CN1 + CN2) {
        const int4* q = (const int4*)(p1 + (j8 - CN1));
        ma = q[0]; mb = q[1];
      } else {
        int v[8];
#pragma unroll
        for (int e = 0; e < 8; ++e) {
          int je = j8 + e;
          v[e] = (je < CN1 + CN2) ? p1[je - CN1] : p2[je - CN1 - CN2];
        }
        ma = make_int4(v[0], v[1], v[2], v[3]);
        mb = make_int4(v[4], v[5], v[6], v[7]);
      }
    } else {
      const int4* q = (const int4*)(p0 + j8);
      ma = q[0]; mb = q[1];
    }
  };

  struct Frags { int4 f0[4], f1[4]; float4 w0a, w0b, w1a, w1b; };
  auto load_frags = [&](int t, Frags& F) {
    const int4* bp0 = WhB + t * 256 + lane;
    const int4* bp1 = WhB + (250 + t) * 256 + lane;
#pragma unroll
    for (int c = 0; c < 4; ++c) { F.f0[c] = bp0[c * 64]; F.f1[c] = bp1[c * 64]; }
    const float* w0 = wh2_0 + t * 32 + kb;
    const float* w1 = wh2_1 + t * 32 + kb;
    F.w0a = *(const float4*)w0; F.w0b = *(const float4*)(w0 + 4);
    F.w1a = *(const float4*)w1; F.w1b = *(const float4*)(w1 + 4);
  };

  auto compute = [&](const int4& ma, const int4& mb, const Frags& F) {
    const int   mv[8] = {ma.x, ma.y, ma.z, ma.w, mb.x, mb.y, mb.z, mb.w};
    const float w0v[8] = {F.w0a.x, F.w0a.y, F.w0a.z, F.w0a.w, F.w0b.x, F.w0b.y, F.w0b.z, F.w0b.w};
    const float w1v[8] = {F.w1a.x, F.w1a.y, F.w1a.z, F.w1a.w, F.w1b.x, F.w1b.y, F.w1b.z, F.w1b.w};
    float q0[8], q1[8];
#pragma unroll
    for (int e = 0; e < 8; ++e) {
      bool on = (mv[e] > 0);
      float xa0 = a1c0 + w0v[e];
      float xb0 = fmaf(ALPHA, w0v[e], b1c0);
      float p0e = EXP2F(fmaxf(xa0, xb0));
      q0[e] = on ? p0e : 0.f;
      float xa1 = a1c1 + w1v[e];
      float xb1 = fmaf(ALPHA, w1v[e], b1c1);
      float p1e = EXP2F(fmaxf(xa1, xb1));
      q1[e] = on ? p1e : 0.f;
    }
    sp0 += ((q0[0] + q0[1]) + (q0[2] + q0[3])) + ((q0[4] + q0[5]) + (q0[6] + q0[7]));
    sp1 += ((q1[0] + q1[1]) + (q1[2] + q1[3])) + ((q1[4] + q1[5]) + (q1[6] + q1[7]));
    B16x8 af0, af1;
#pragma unroll
    for (int e2 = 0; e2 < 4; ++e2) {
      af0.u[e2] = pack2_bf16(q0[2 * e2], q0[2 * e2 + 1]);
      af1.u[e2] = pack2_bf16(q1[2 * e2], q1[2 * e2 + 1]);
    }
    B16x8 b;
    b.i4 = F.f0[0]; a0_0 = __builtin_amdgcn_mfma_f32_16x16x32_bf16(af0.s8, b.s8, a0_0, 0, 0, 0);
    b.i4 = F.f0[1]; a0_1 = __builtin_amdgcn_mfma_f32_16x16x32_bf16(af0.s8, b.s8, a0_1, 0, 0, 0);
    b.i4 = F.f0[2]; a0_2 = __builtin_amdgcn_mfma_f32_16x16x32_bf16(af0.s8, b.s8, a0_2, 0, 0, 0);
    b.i4 = F.f0[3]; a0_3 = __builtin_amdgcn_mfma_f32_16x16x32_bf16(af0.s8, b.s8, a0_3, 0, 0, 0);
    b.i4 = F.f1[0]; a1_0 = __builtin_amdgcn_mfma_f32_16x16x32_bf16(af1.s8, b.s8, a1_0, 0, 0, 0);
    b.i4 = F.f1[1]; a1_1 = __builtin_amdgcn_mfma_f32_16x16x32_bf16(af1.s8, b.s8, a1_1, 0, 0, 0);
    b.i4 = F.f1[2]; a1_2 = __builtin_amdgcn_mfma_f32_16x16x32_bf16(af1.s8, b.s8, a1_2, 0, 0, 0);
    b.i4 = F.f1[3]; a1_3 = __builtin_amdgcn_mfma_f32_16x16x32_bf16(af1.s8, b.s8, a1_3, 0, 0, 0);
  };

  // pipeline: mask 3 ahead (HBM), frags 1 ahead (L2)
  int4 ma0, mb0, ma1, mb1, ma2, mb2, ma3, mb3;
  Frags Fc, Fn;
  load_mask(t0, ma0, mb0);
  load_mask(min(t0 + 1, t1 - 1), ma1, mb1);
  load_mask(min(t0 + 2, t1 - 1), ma2, mb2);
  load_frags(t0, Fc);
  for (int t = t0; t < t1; ++t) {
    load_frags(min(t + 1, t1 - 1), Fn);
    load_mask(min(t + 3, t1 - 1), ma3, mb3);
    compute(ma0, mb0, Fc);
    ma0 = ma1; mb0 = mb1; ma1 = ma2; mb1 = mb2; ma2 = ma3; mb2 = mb3;
    Fc = Fn;
  }

  // row sums: row m lives on lanes {m, m+16, m+32, m+48}
  sp0 += __shfl_xor(sp0, 16, 64); sp0 += __shfl_xor(sp0, 32, 64);
  sp1 += __shfl_xor(sp1, 16, 64); sp1 += __shfl_xor(sp1, 32, 64);
  const int base0 = (jy * 2 + 0) * NTOT + rowblk * 16;
  const int base1 = (jy * 2 + 1) * NTOT + rowblk * 16;
  if (lane < 16) {
    partS[base0 + lane] = sp0;
    partS[base1 + lane] = sp1;
  }

  // C layout: col = lane&15 (feature), row = g*4 + q (node)
  float* o0 = partAcc + base0 * OUTF;
  float* o1 = partAcc + base1 * OUTF;
#pragma unroll
  for (int q = 0; q < 4; ++q) {
    const int row = g * 4 + q;
    o0[row * OUTF +      m] = a0_0[q];
    o0[row * OUTF + 16 + m] = a0_1[q];
    o0[row * OUTF + 32 + m] = a0_2[q];
    o0[row * OUTF + 48 + m] = a0_3[q];
    o1[row * OUTF +      m] = a1_0[q];
    o1[row * OUTF + 16 + m] = a1_1[q];
    o1[row * OUTF + 32 + m] = a1_2[q];
    o1[row * OUTF + 48 + m] = a1_3[q];
  }
}

// ---------------- k_final: combine njy + /s + ELU + log_softmax + store -----
__global__ void k_final(const float* __restrict__ partAcc, const float* __restrict__ partS,
                        int njy, float* __restrict__ out) {
  const int wave = threadIdx.x >> 6, lane = threadIdx.x & 63;
  const int n = blockIdx.x * 4 + wave;
  float x[2];
#pragma unroll
  for (int hd = 0; hd < 2; ++hd) {
    float a = 0.f, s = 0.f;
    for (int jy = 0; jy < njy; ++jy) {
      a += partAcc[((jy * 2 + hd) * NTOT + n) * OUTF + lane];
      s += partS[(jy * 2 + hd) * NTOT + n];
    }
    float mid = a / s;
    x[hd] = mid > 0.f ? mid : (__expf(mid) - 1.f);   // ELU(alpha=1)
  }
  float mx = fmaxf(x[0], x[1]);
  for (int d = 32; d; d >>= 1) mx = fmaxf(mx, __shfl_xor(mx, d, 64));
  float se = __expf(x[0] - mx) + __expf(x[1] - mx);
  for (int d = 32; d; d >>= 1) se += __shfl_xor(se, d, 64);
  const float lse = mx + __logf(se);
  const int orow = (n >= CN1 + CN2) ? (n - CN1 - CN2) : (n + CN3);
  out[orow * 128 + lane]      = x[0] - lse;
  out[orow * 128 + 64 + lane] = x[1] - lse;
}

__global__ void k_sentinel(float* __restrict__ out, float v) {
  out[blockIdx.x * 256 + threadIdx.x] = v;
}

// ---------------------------------------------------------------------------
extern "C" void kernel_launch(void* const* d_in, const int* in_sizes, int n_in,
                              void* d_out, int out_size, void* d_ws, size_t ws_size,
                              hipStream_t stream) {
  float* outf = (float*)d_out;

  static const int EXP[12] = {1024000, 9000000, 6250000, 6250000, 7500000, 7500000,
                              6250000, 7500000, 7500000, 6250000, 16384, 256};
  bool exact = (n_in == 12);
  if (exact) for (int i = 0; i < 12; ++i) if (in_sizes[i] != EXP[i]) { exact = false; break; }

  // ws layout: Wh1s 64000 | Wh2s 64000 | M2s 256 | WhB 2,048,000 |
  //            partS njy*64,000 | Whf 4,096,000 / partAcc njy*4,096,000 (overlay)
  const size_t FIXED = 64000 + 64000 + 256 + 2048000;   // = 2,176,256
  int njy = 0;
  for (int cand = 4; cand >= 1; cand >>= 1) {
    size_t need = FIXED + (size_t)cand * 64000 +
                  ((size_t)(cand > 1 ? cand : 1)) * 4096000;
    if (ws_size >= need) { njy = cand; break; }
  }
  if (!exact || njy == 0) {
    k_sentinel<<<dim3(4000), dim3(256), 0, stream>>>(outf, -148.0f);
    return;
  }

  const float* h  = (const float*)d_in[0];
  const int* A1  = (const int*)d_in[1];
  const int* A2  = (const int*)d_in[2];
  const int* A3  = (const int*)d_in[3];
  const int* A12 = (const int*)d_in[4];
  const int* A13 = (const int*)d_in[5];
  const int* A23 = (const int*)d_in[6];
  const int* A21 = (const int*)d_in[7];
  const int* A31 = (const int*)d_in[8];
  const int* A32 = (const int*)d_in[9];
  const float* Ws = (const float*)d_in[10];
  const float* ap = (const float*)d_in[11];

  char* w = (char*)d_ws;
  float* Wh1s    = (float*)(w);
  float* Wh2s    = (float*)(w + 64000);
  float* M2s     = (float*)(w + 128000);
  int4*  WhB     = (int4*) (w + 128256);
  float* partS   = (float*)(w + 2176256);
  float* Whf     = (float*)(w + 2176256 + (size_t)njy * 64000);
  float* partAcc = Whf;                           // overlay (Whf dead after k_bpack)

  k_wh       <<<dim3(4000),     dim3(128), 0, stream>>>(h, Ws, ap, Whf, Wh1s, Wh2s);
  k_m2       <<<dim3(2),        dim3(256), 0, stream>>>(Wh2s, M2s);
  k_bpack    <<<dim3(500),      dim3(256), 0, stream>>>(Whf, WhB);
  k_attn_mfma<<<dim3(250, njy), dim3(128), 0, stream>>>(A1, A12, A13, A21, A2, A23, A31, A32, A3,
                                                        Wh1s, Wh2s, M2s, WhB, partAcc, partS);
  k_final    <<<dim3(2000),     dim3(256), 0, stream>>>(partAcc, partS, njy, outf);
}